// Round 12
// baseline (113.858 us; speedup 1.0000x reference)
//
#include <hip/hip_runtime.h>

// 2-layer GCN, N=100000 (F0=5, F1=16, F2=1), E=3200000.
// Round-5 pipeline with k_sortbin replaced by k_sortslot: per-node FIXED-SLOT
// scatter (1 LDS atomic/edge, placement addr = atomic return; no hist/scan).
//   k_place:    LDS counting-sort of 4096-edge chunks into bin regions
//               (2 LDS atomics/edge), coalesced bin-run write-out. [proven 48us]
//   k_sortslot: per-bin scatter into slots[node*72 + slot] (1 atomic/edge),
//               full-slot-block coalesced writeout, deg/dinv/y epilogue.
//   k_agg1/2:   atomic-free segmented gathers over per-node slot runs.
//   y[i]   = dinv[i]*x[i] (5 floats padded to 8)
//   z[i]   = dinv[i]*(relu(dinv[i]*(sum y[s] + y[i])@W1 + b1)@W2)
//   out[i] = dinv[i]*(sum z[s] + z[i]) + b2
//
// DS-atomic ledger: place 2 + sortslot 1 = 3 serialized lane-ops/edge
// (round-5 had 4). Each ~4.5cy x 12.5K edges/CU ~ 23.6us.

constexpr int CHUNK = 4096;   // edges per k_place block
constexpr int RANGE = 256;    // nodes per bin
constexpr int CAP   = 9216;   // compact slots per bin region (lambda 8192 + 11 sigma)
constexpr int CAPN  = 72;     // slots per node (lambda 32; P(deg>72) ~ 5e-10)
constexpr int SLOTB = RANGE * CAPN;  // 18432 ints per bin slot-block

__global__ void k_init(int* __restrict__ cursor, int nb) {
  int b = blockIdx.x * blockDim.x + threadIdx.x;
  if (b < nb) cursor[b] = b * CAP;
}

// ---- pass 1: LDS counting-sort each chunk into bin regions (round-5) -------
__global__ void __launch_bounds__(256) k_place(const int* __restrict__ src,
                                               const int* __restrict__ dst,
                                               int* __restrict__ cursor,
                                               int* __restrict__ bins,
                                               int e, int nb) {
  __shared__ int entry4[CHUNK];
  __shared__ short bin2[CHUNK];
  __shared__ int hist[512], scan[512], lofs[512], base[512], pcur[512];
  int t = threadIdx.x;
  int e0 = blockIdx.x * CHUNK;
  int cnt = e - e0; if (cnt > CHUNK) cnt = CHUNK;

  for (int b = t; b < 512; b += 256) hist[b] = 0;
  __syncthreads();
  for (int i = t; i < cnt; i += 256) atomicAdd(&hist[dst[e0 + i] >> 8], 1);
  __syncthreads();
  scan[t] = hist[t]; scan[t + 256] = hist[t + 256];
  __syncthreads();
  for (int d = 1; d < 512; d <<= 1) {
    int v0 = (t >= d) ? scan[t - d] : 0;
    int v1 = (t + 256 >= d) ? scan[t + 256 - d] : 0;
    __syncthreads();
    scan[t] += v0; scan[t + 256] += v1;
    __syncthreads();
  }
  for (int b = t; b < 512; b += 256) {
    int lo = scan[b] - hist[b];
    lofs[b] = lo;
    pcur[b] = lo;
    if (b < nb && hist[b]) base[b] = atomicAdd(&cursor[b], hist[b]);  // absolute
  }
  __syncthreads();
  for (int i = t; i < cnt; i += 256) {
    int d = dst[e0 + i];
    int b = d >> 8;
    int slot = atomicAdd(&pcur[b], 1);
    entry4[slot] = ((d & 255) << 24) | src[e0 + i];
    bin2[slot] = (short)b;
  }
  __syncthreads();
  for (int i = t; i < cnt; i += 256) {
    int b = bin2[i];
    bins[base[b] + (i - lofs[b])] = entry4[i];
  }
}

// ---- pass 2: fixed-slot scatter (1 atomic/edge) + deg/dinv/y epilogue ------
__global__ void __launch_bounds__(1024) k_sortslot(const int* __restrict__ bins,
                                                   const int* __restrict__ cursor,
                                                   int* __restrict__ slots,
                                                   int* __restrict__ deg_g,
                                                   const float* __restrict__ x,
                                                   float* __restrict__ dinv,
                                                   float* __restrict__ y, int n) {
  __shared__ int lists[SLOTB];     // 72 KB
  __shared__ int pcur[RANGE];
  int t = threadIdx.x;
  int b = blockIdx.x;
  int bse = b * CAP;
  int len = cursor[b] - bse;
  if (t < RANGE) pcur[t] = 0;
  __syncthreads();

  // single pass: read compact bin entries, scatter into per-node slots
  for (int k = t; k < len; k += 1024) {
    unsigned e4 = (unsigned)bins[bse + k];
    int dl = (int)(e4 >> 24);
    int slot = atomicAdd(&pcur[dl], 1);
    if (slot < CAPN) lists[dl * CAPN + slot] = (int)(e4 & 0xFFFFFF);
  }
  __syncthreads();

  // coalesced write-out of the whole slot block (junk in unused slots is
  // never read: agg kernels stop at deg)
  size_t gb = (size_t)b * SLOTB;
  for (int k = t; k < SLOTB; k += 1024) slots[gb + k] = lists[k];

  if (t < RANGE) {
    int node = b * RANGE + t;
    if (node < n) {
      int cnt = pcur[t];                 // true in-degree (unclamped)
      deg_g[node] = min(cnt, CAPN);      // walk length for agg kernels
      float dv = rsqrtf((float)(cnt + 1));
      dinv[node] = dv;
      float4 a, c;
      a.x = dv * x[node * 5 + 0];
      a.y = dv * x[node * 5 + 1];
      a.z = dv * x[node * 5 + 2];
      a.w = dv * x[node * 5 + 3];
      c.x = dv * x[node * 5 + 4];
      c.y = c.z = c.w = 0.f;
      ((float4*)y)[(size_t)node * 2 + 0] = a;
      ((float4*)y)[(size_t)node * 2 + 1] = c;
    }
  }
}

// ---- pass 3: layer-1 — atomic-free slot-run gather + fused W1/relu/W2 ------
__global__ void __launch_bounds__(1024) k_agg1(const int* __restrict__ slots,
                                               const int* __restrict__ deg_g,
                                               const float* __restrict__ y,
                                               const float* __restrict__ dinv,
                                               const float* __restrict__ W1,
                                               const float* __restrict__ b1,
                                               const float* __restrict__ W2,
                                               float* __restrict__ z, int n) {
  __shared__ float sW1[80], sb1[16], sW2[16];
  int t = threadIdx.x;
  if (t < 80) sW1[t] = W1[t];
  else if (t < 96) sb1[t - 80] = b1[t - 80];
  else if (t < 112) sW2[t - 96] = W2[t - 96];
  __syncthreads();
  int g = t >> 2, l4 = t & 3;
  int b = blockIdx.x;
  int node = b * RANGE + g;
  if (node >= n) return;
  const int* run = slots + (size_t)node * CAPN;
  int r1 = deg_g[node];
  float a0 = 0.f, a1 = 0.f, a2 = 0.f, a3 = 0.f, a4 = 0.f;
  for (int k = l4; k < r1; k += 4) {
    int s = run[k];
    float4 v = ((const float4*)y)[(size_t)s * 2];
    float v4 = y[(size_t)s * 8 + 4];
    a0 += v.x; a1 += v.y; a2 += v.z; a3 += v.w; a4 += v4;
  }
  a0 += __shfl_xor(a0, 1); a0 += __shfl_xor(a0, 2);
  a1 += __shfl_xor(a1, 1); a1 += __shfl_xor(a1, 2);
  a2 += __shfl_xor(a2, 1); a2 += __shfl_xor(a2, 2);
  a3 += __shfl_xor(a3, 1); a3 += __shfl_xor(a3, 2);
  a4 += __shfl_xor(a4, 1); a4 += __shfl_xor(a4, 2);
  float4 ys = ((const float4*)y)[(size_t)node * 2];
  float ys4 = y[(size_t)node * 8 + 4];
  float A0 = a0 + ys.x, A1 = a1 + ys.y, A2 = a2 + ys.z, A3 = a3 + ys.w, A4 = a4 + ys4;
  float di = dinv[node];
  float o = 0.f;
#pragma unroll
  for (int fi = 0; fi < 4; ++fi) {
    int f = l4 * 4 + fi;
    float h = A0 * sW1[0 * 16 + f];
    h = fmaf(A1, sW1[1 * 16 + f], h);
    h = fmaf(A2, sW1[2 * 16 + f], h);
    h = fmaf(A3, sW1[3 * 16 + f], h);
    h = fmaf(A4, sW1[4 * 16 + f], h);
    float v = fmaxf(fmaf(di, h, sb1[f]), 0.f);
    o = fmaf(v, sW2[f], o);
  }
  o += __shfl_xor(o, 1);
  o += __shfl_xor(o, 2);
  if (l4 == 0) z[node] = di * o;
}

// ---- pass 4: layer-2 — atomic-free slot-run gather of scalar z -------------
__global__ void __launch_bounds__(1024) k_agg2(const int* __restrict__ slots,
                                               const int* __restrict__ deg_g,
                                               const float* __restrict__ z,
                                               const float* __restrict__ dinv,
                                               const float* __restrict__ b2,
                                               float* __restrict__ out, int n) {
  int t = threadIdx.x;
  int g = t >> 2, l4 = t & 3;
  int b = blockIdx.x;
  int node = b * RANGE + g;
  if (node >= n) return;
  const int* run = slots + (size_t)node * CAPN;
  int r1 = deg_g[node];
  float a = 0.f;
  for (int k = l4; k < r1; k += 4) a += z[run[k]];
  a += __shfl_xor(a, 1);
  a += __shfl_xor(a, 2);
  if (l4 == 0) out[node] = fmaf(dinv[node], a + z[node], b2[0]);
}

extern "C" void kernel_launch(void* const* d_in, const int* in_sizes, int n_in,
                              void* d_out, int out_size, void* d_ws, size_t ws_size,
                              hipStream_t stream) {
  const float* x  = (const float*)d_in[0];
  const float* W1 = (const float*)d_in[1];
  const float* b1 = (const float*)d_in[2];
  const float* W2 = (const float*)d_in[3];
  const float* b2 = (const float*)d_in[4];
  const int*   ei = (const int*)d_in[5];

  int n = in_sizes[0] / 5;
  int e = in_sizes[5] / 2;
  const int* src = ei;
  const int* dst = ei + e;
  int nb = (n + RANGE - 1) / RANGE;  // 391

  char* ws = (char*)d_ws;
  int*   slots  = (int*)ws;   ws += (size_t)nb * SLOTB * sizeof(int);   // 28.8 MB
  int*   bins   = (int*)ws;   ws += (size_t)nb * CAP * sizeof(int);     // 14.4 MB
  float* y      = (float*)ws; ws += (size_t)nb * RANGE * 8 * sizeof(float);  // 12.8 MB
  int*   deg    = (int*)ws;   ws += (size_t)n * sizeof(int);
  float* dinv   = (float*)ws; ws += (size_t)n * sizeof(float);
  float* z      = (float*)ws; ws += (size_t)n * sizeof(float);
  int*   cursor = (int*)ws;   ws += (size_t)nb * sizeof(int);

  float* out = (float*)d_out;

  int chunks = (e + CHUNK - 1) / CHUNK;

  k_init<<<(nb + 255) / 256, 256, 0, stream>>>(cursor, nb);
  k_place<<<chunks, 256, 0, stream>>>(src, dst, cursor, bins, e, nb);
  k_sortslot<<<nb, 1024, 0, stream>>>(bins, cursor, slots, deg, x, dinv, y, n);
  k_agg1<<<nb, 1024, 0, stream>>>(slots, deg, y, dinv, W1, b1, W2, z, n);
  k_agg2<<<nb, 1024, 0, stream>>>(slots, deg, z, dinv, b2, out, n);
}

// Round 13
// 111.292 us; speedup vs baseline: 1.0231x; 1.0231x over previous
//
#include <hip/hip_runtime.h>

// 2-layer GCN, N=100000 (F0=5, F1=16, F2=1), E=3200000.
// Round-5 configuration — best measured (109.9/110.5us), restored exactly.
//   k_place:   LDS counting-sort of 4096-edge chunks into 256-node bin regions
//              (2 LDS atomics/edge), coalesced bin-run write-out.
//   k_sortbin: per-bin LDS counting sort by dl (2 LDS atomics/edge), emits
//              dst-sorted src lists + run offsets + deg->dinv + y = dinv*x.
//   k_agg1/2:  atomic-free segmented gathers (4 lanes/node, shfl_xor reduce).
//   y[i]   = dinv[i]*x[i] (5 floats padded to 8)
//   z[i]   = dinv[i]*(relu(dinv[i]*(sum_run y[s] + y[i])@W1 + b1)@W2)
//   out[i] = dinv[i]*(sum_run z[s] + z[i]) + b2
//
// Structural ceiling (measured, rounds 5-12): the pipeline is DS-atomic-pipe
// bound: 12.5K edges/CU x 4 serialized LDS-atomic lane-ops x ~4.5cy ~ 94us,
// + ~16us agg/launch tails = ~110us. Alternatives measured and all worse:
// 3-atomic slot-scatter 113.9, 3-atomic list-place 124.9, 3-atomic ballot-hist
// 122.9, 2-atomic ballot-radix 138-147. Occupancy-insensitive (r3->r4: 4x
// occupancy = 0 speedup). Memory roofline ~14us — not the binding constraint.

constexpr int CHUNK = 4096;   // edges per k_place block
constexpr int RANGE = 256;    // nodes per bin
constexpr int CAP   = 12288;  // slots per bin region (max bin ~8.6K)

__global__ void k_init(int* __restrict__ cursor, int nb) {
  int b = blockIdx.x * blockDim.x + threadIdx.x;
  if (b < nb) cursor[b] = b * CAP;
}

// ---- pass 1: LDS counting-sort each chunk into bin regions (coalesced) -----
__global__ void __launch_bounds__(256) k_place(const int* __restrict__ src,
                                               const int* __restrict__ dst,
                                               int* __restrict__ cursor,
                                               int* __restrict__ bins,
                                               int e, int nb) {
  __shared__ int entry4[CHUNK];
  __shared__ short bin2[CHUNK];
  __shared__ int hist[512], scan[512], lofs[512], base[512], pcur[512];
  int t = threadIdx.x;
  int e0 = blockIdx.x * CHUNK;
  int cnt = e - e0; if (cnt > CHUNK) cnt = CHUNK;

  for (int b = t; b < 512; b += 256) hist[b] = 0;
  __syncthreads();
  for (int i = t; i < cnt; i += 256) atomicAdd(&hist[dst[e0 + i] >> 8], 1);
  __syncthreads();
  scan[t] = hist[t]; scan[t + 256] = hist[t + 256];
  __syncthreads();
  for (int d = 1; d < 512; d <<= 1) {
    int v0 = (t >= d) ? scan[t - d] : 0;
    int v1 = (t + 256 >= d) ? scan[t + 256 - d] : 0;
    __syncthreads();
    scan[t] += v0; scan[t + 256] += v1;
    __syncthreads();
  }
  for (int b = t; b < 512; b += 256) {
    int lo = scan[b] - hist[b];
    lofs[b] = lo;
    pcur[b] = lo;
    if (b < nb && hist[b]) base[b] = atomicAdd(&cursor[b], hist[b]);  // absolute
  }
  __syncthreads();
  for (int i = t; i < cnt; i += 256) {
    int d = dst[e0 + i];
    int b = d >> 8;
    int slot = atomicAdd(&pcur[b], 1);
    entry4[slot] = ((d & 255) << 24) | src[e0 + i];
    bin2[slot] = (short)b;
  }
  __syncthreads();
  for (int i = t; i < cnt; i += 256) {
    int b = bin2[i];
    bins[base[b] + (i - lofs[b])] = entry4[i];
  }
}

// ---- pass 2: per-bin counting sort by dl; emit run offsets, deg->dinv, y ----
__global__ void __launch_bounds__(1024) k_sortbin(int* __restrict__ bins,
                                                  const int* __restrict__ cursor,
                                                  const float* __restrict__ x,
                                                  float* __restrict__ dinv,
                                                  float* __restrict__ y,
                                                  int* __restrict__ roff, int n) {
  __shared__ int sorted[CAP];
  __shared__ int hist[RANGE], sc[RANGE], pcur[RANGE];
  int t = threadIdx.x;
  int b = blockIdx.x;
  int bse = b * CAP;
  int len = cursor[b] - bse;
  if (t < RANGE) hist[t] = 0;
  __syncthreads();
  for (int k = t; k < len; k += 1024)
    atomicAdd(&hist[((unsigned)bins[bse + k]) >> 24], 1);
  __syncthreads();
  if (t < RANGE) sc[t] = hist[t];
  __syncthreads();
  for (int d = 1; d < RANGE; d <<= 1) {
    int v = 0;
    if (t < RANGE && t >= d) v = sc[t - d];
    __syncthreads();
    if (t < RANGE) sc[t] += v;
    __syncthreads();
  }
  if (t < RANGE) pcur[t] = sc[t] - hist[t];
  __syncthreads();
  for (int k = t; k < len; k += 1024) {
    unsigned e4 = (unsigned)bins[bse + k];
    int slot = atomicAdd(&pcur[e4 >> 24], 1);
    sorted[slot] = (int)(e4 & 0xFFFFFF);
  }
  __syncthreads();
  for (int k = t; k < len; k += 1024) bins[bse + k] = sorted[k];
  if (t < RANGE) roff[b * (RANGE + 1) + t] = bse + sc[t] - hist[t];
  if (t == 0) roff[b * (RANGE + 1) + RANGE] = bse + len;
  if (t < RANGE) {
    int node = b * RANGE + t;
    if (node < n) {
      float dv = rsqrtf((float)(hist[t] + 1));
      dinv[node] = dv;
      float4 a, c;
      a.x = dv * x[node * 5 + 0];
      a.y = dv * x[node * 5 + 1];
      a.z = dv * x[node * 5 + 2];
      a.w = dv * x[node * 5 + 3];
      c.x = dv * x[node * 5 + 4];
      c.y = c.z = c.w = 0.f;
      ((float4*)y)[(size_t)node * 2 + 0] = a;
      ((float4*)y)[(size_t)node * 2 + 1] = c;
    }
  }
}

// ---- pass 3: layer-1 — atomic-free segmented gather + fused W1/relu/W2 -----
__global__ void __launch_bounds__(1024) k_agg1(const int* __restrict__ bins,
                                               const int* __restrict__ roff,
                                               const float* __restrict__ y,
                                               const float* __restrict__ dinv,
                                               const float* __restrict__ W1,
                                               const float* __restrict__ b1,
                                               const float* __restrict__ W2,
                                               float* __restrict__ z, int n) {
  __shared__ float sW1[80], sb1[16], sW2[16];
  int t = threadIdx.x;
  if (t < 80) sW1[t] = W1[t];
  else if (t < 96) sb1[t - 80] = b1[t - 80];
  else if (t < 112) sW2[t - 96] = W2[t - 96];
  __syncthreads();
  int g = t >> 2, l4 = t & 3;
  int b = blockIdx.x;
  int node = b * RANGE + g;
  if (node >= n) return;
  int r0 = roff[b * (RANGE + 1) + g];
  int r1 = roff[b * (RANGE + 1) + g + 1];
  float a0 = 0.f, a1 = 0.f, a2 = 0.f, a3 = 0.f, a4 = 0.f;
  for (int k = r0 + l4; k < r1; k += 4) {
    int s = bins[k];
    float4 v = ((const float4*)y)[(size_t)s * 2];
    float v4 = y[(size_t)s * 8 + 4];
    a0 += v.x; a1 += v.y; a2 += v.z; a3 += v.w; a4 += v4;
  }
  a0 += __shfl_xor(a0, 1); a0 += __shfl_xor(a0, 2);
  a1 += __shfl_xor(a1, 1); a1 += __shfl_xor(a1, 2);
  a2 += __shfl_xor(a2, 1); a2 += __shfl_xor(a2, 2);
  a3 += __shfl_xor(a3, 1); a3 += __shfl_xor(a3, 2);
  a4 += __shfl_xor(a4, 1); a4 += __shfl_xor(a4, 2);
  float4 ys = ((const float4*)y)[(size_t)node * 2];
  float ys4 = y[(size_t)node * 8 + 4];
  float A0 = a0 + ys.x, A1 = a1 + ys.y, A2 = a2 + ys.z, A3 = a3 + ys.w, A4 = a4 + ys4;
  float di = dinv[node];
  float o = 0.f;
#pragma unroll
  for (int fi = 0; fi < 4; ++fi) {
    int f = l4 * 4 + fi;
    float h = A0 * sW1[0 * 16 + f];
    h = fmaf(A1, sW1[1 * 16 + f], h);
    h = fmaf(A2, sW1[2 * 16 + f], h);
    h = fmaf(A3, sW1[3 * 16 + f], h);
    h = fmaf(A4, sW1[4 * 16 + f], h);
    float v = fmaxf(fmaf(di, h, sb1[f]), 0.f);
    o = fmaf(v, sW2[f], o);
  }
  o += __shfl_xor(o, 1);
  o += __shfl_xor(o, 2);
  if (l4 == 0) z[node] = di * o;
}

// ---- pass 4: layer-2 — atomic-free segmented gather of scalar z ------------
__global__ void __launch_bounds__(1024) k_agg2(const int* __restrict__ bins,
                                               const int* __restrict__ roff,
                                               const float* __restrict__ z,
                                               const float* __restrict__ dinv,
                                               const float* __restrict__ b2,
                                               float* __restrict__ out, int n) {
  int t = threadIdx.x;
  int g = t >> 2, l4 = t & 3;
  int b = blockIdx.x;
  int node = b * RANGE + g;
  if (node >= n) return;
  int r0 = roff[b * (RANGE + 1) + g];
  int r1 = roff[b * (RANGE + 1) + g + 1];
  float a = 0.f;
  for (int k = r0 + l4; k < r1; k += 4) a += z[bins[k]];
  a += __shfl_xor(a, 1);
  a += __shfl_xor(a, 2);
  if (l4 == 0) out[node] = fmaf(dinv[node], a + z[node], b2[0]);
}

extern "C" void kernel_launch(void* const* d_in, const int* in_sizes, int n_in,
                              void* d_out, int out_size, void* d_ws, size_t ws_size,
                              hipStream_t stream) {
  const float* x  = (const float*)d_in[0];
  const float* W1 = (const float*)d_in[1];
  const float* b1 = (const float*)d_in[2];
  const float* W2 = (const float*)d_in[3];
  const float* b2 = (const float*)d_in[4];
  const int*   ei = (const int*)d_in[5];

  int n = in_sizes[0] / 5;
  int e = in_sizes[5] / 2;
  const int* src = ei;
  const int* dst = ei + e;
  int nb = (n + RANGE - 1) / RANGE;  // 391

  char* ws = (char*)d_ws;
  int*   bins   = (int*)ws;   ws += (size_t)nb * CAP * sizeof(int);
  float* y      = (float*)ws; ws += (size_t)nb * RANGE * 8 * sizeof(float);
  float* dinv   = (float*)ws; ws += (size_t)n * sizeof(float);
  float* z      = (float*)ws; ws += (size_t)n * sizeof(float);
  int*   cursor = (int*)ws;   ws += (size_t)nb * sizeof(int);
  int*   roff   = (int*)ws;   ws += (size_t)nb * (RANGE + 1) * sizeof(int);

  float* out = (float*)d_out;

  int chunks = (e + CHUNK - 1) / CHUNK;

  k_init<<<(nb + 255) / 256, 256, 0, stream>>>(cursor, nb);
  k_place<<<chunks, 256, 0, stream>>>(src, dst, cursor, bins, e, nb);
  k_sortbin<<<nb, 1024, 0, stream>>>(bins, cursor, x, dinv, y, roff, n);
  k_agg1<<<nb, 1024, 0, stream>>>(bins, roff, y, dinv, W1, b1, W2, z, n);
  k_agg2<<<nb, 1024, 0, stream>>>(bins, roff, z, dinv, b2, out, n);
}